// Round 13
// baseline (149.360 us; speedup 1.0000x reference)
//
#include <hip/hip_runtime.h>
#include <math.h>

// B=16, H=W=32, C=512, D=128/group, S=1, R=8
#define NTOK 16384
#define NC 512
#define ND 128
#define NCH 64   // scan chunks per (b,g)
#define CST 16   // steps per chunk

typedef __attribute__((ext_vector_type(8))) short bf16x8;
typedef __attribute__((ext_vector_type(4))) float f32x4;

#define LOG2E 1.4426950408889634f
#define LN2   0.6931471805599453f

__device__ __forceinline__ float fexp(float x){ return __builtin_amdgcn_exp2f(x * LOG2E); }
__device__ __forceinline__ float flog(float x){ return __builtin_amdgcn_logf(x) * LN2; }
__device__ __forceinline__ float sigf(float x){ return 1.f/(1.f + fexp(-x)); }

__device__ __forceinline__ float b2f(ushort u){ unsigned x = ((unsigned)u)<<16; return __builtin_bit_cast(float,x); }
__device__ __forceinline__ ushort f2b(float f){
  unsigned u = __builtin_bit_cast(unsigned,f);
  u += 0x7fff + ((u>>16)&1);
  return (ushort)(u>>16);
}

__device__ __forceinline__ int perm_pos(int g, int l){
  switch(g){
    case 0: return l;
    case 1: return ((l & 31) << 5) | (l >> 5);
    case 2: return 1023 - l;
    default:{ int ll = 1023 - l; return ((ll & 31) << 5) | (ll >> 5); }
  }
}

__device__ __forceinline__ void gload16(const void* g, void* l){
  __builtin_amdgcn_global_load_lds((const __attribute__((address_space(1))) void*)g,
                                   (__attribute__((address_space(3))) void*)l, 16, 0, 0);
}

// ---------------- K1: LayerNorm over C=512 + folded weight->bf16 conversion ----------------
__global__ __launch_bounds__(256) void k_ln512(const float* __restrict__ x,
    const float* __restrict__ w, const float* __restrict__ b, ushort* __restrict__ out,
    const float* __restrict__ s1, int n1, ushort* __restrict__ d1,
    const float* __restrict__ s2, int n2, ushort* __restrict__ d2,
    const float* __restrict__ s3, int n3, ushort* __restrict__ d3,
    const float* __restrict__ s4, int n4, ushort* __restrict__ d4){
  // folded fp32->bf16 weight conversion (1 elem/thread; grid 4096*256 >= n_total)
  int gidx = blockIdx.x*256 + threadIdx.x;
  if (gidx < n1) d1[gidx] = f2b(s1[gidx]);
  else if (gidx < n1+n2) d2[gidx-n1] = f2b(s2[gidx-n1]);
  else if (gidx < n1+n2+n3) d3[gidx-n1-n2] = f2b(s3[gidx-n1-n2]);
  else if (gidx < n1+n2+n3+n4) d4[gidx-n1-n2-n3] = f2b(s4[gidx-n1-n2-n3]);

  int wv = threadIdx.x >> 6, lane = threadIdx.x & 63;
  int t = blockIdx.x*4 + wv;
  const float* xr = x + (size_t)t*NC + lane*8;
  float4 a = *(const float4*)xr;
  float4 c = *(const float4*)(xr+4);
  float e[8] = {a.x,a.y,a.z,a.w,c.x,c.y,c.z,c.w};
  float s = 0.f, sq = 0.f;
  #pragma unroll
  for (int i=0;i<8;i++){ s += e[i]; sq += e[i]*e[i]; }
  #pragma unroll
  for (int o=1;o<64;o<<=1){ s += __shfl_xor(s,o); sq += __shfl_xor(sq,o); }
  float m = s*(1.f/NC);
  float var = sq*(1.f/NC) - m*m;
  float rs = rsqrtf(var + 1e-5f);
  const float4* wr = (const float4*)(w + lane*8);
  const float4* br = (const float4*)(b + lane*8);
  float4 w0 = wr[0], w1 = wr[1], b0 = br[0], b1 = br[1];
  float wv8[8] = {w0.x,w0.y,w0.z,w0.w,w1.x,w1.y,w1.z,w1.w};
  float bv8[8] = {b0.x,b0.y,b0.z,b0.w,b1.x,b1.y,b1.z,b1.w};
  bf16x8 o8;
  #pragma unroll
  for (int i=0;i<8;i++) ((ushort*)&o8)[i] = f2b((e[i]-m)*rs*wv8[i]+bv8[i]);
  *(bf16x8*)(out + (size_t)t*NC + lane*8) = o8;
}

// ---------------- K2: column mean, 2-stage ----------------
__global__ __launch_bounds__(512) void k_cm1(const ushort* __restrict__ xn,
    float* __restrict__ part){
  int c = threadIdx.x;
  const ushort* base = xn + ((size_t)blockIdx.x*32)*NC + c;
  float acc = 0.f;
  for (int n=0;n<32;n++) acc += b2f(base[(size_t)n*NC]);
  part[(size_t)blockIdx.x*NC + c] = acc;
}
__global__ __launch_bounds__(512) void k_cm2(const float* __restrict__ part,
    float* __restrict__ zavg){
  int b = blockIdx.x, c = threadIdx.x;
  float acc = 0.f;
  for (int i=0;i<32;i++) acc += part[(size_t)(b*32+i)*NC + c];
  zavg[b*NC+c] = acc * (1.f/1024.f);
}

// ---------------- K3: ECA + FC gate; wave-per-output ----------------
__global__ __launch_bounds__(256) void k_gate(const float* __restrict__ zavg,
    const float* __restrict__ fcw, const float* __restrict__ fcb,
    const float* __restrict__ ew, float* __restrict__ gate){
  __shared__ float za[NC];
  int b = blockIdx.x >> 7, og = blockIdx.x & 127;
  int tid = threadIdx.x, lane = tid & 63, wv = tid >> 6;
  za[tid]     = zavg[b*NC + tid];
  za[tid+256] = zavg[b*NC + tid + 256];
  __syncthreads();
  int o = og*4 + wv;
  const float* wr = fcw + (size_t)o*NC;
  float acc = 0.f;
  #pragma unroll
  for (int i=0;i<8;i++) acc += za[lane + i*64]*wr[lane + i*64];
  #pragma unroll
  for (int off=1;off<64;off<<=1) acc += __shfl_xor(acc, off);
  if (lane==0){
    float left  = (o>0)    ? za[o-1] : 0.f;
    float right = (o<NC-1) ? za[o+1] : 0.f;
    float ye = ew[0]*left + ew[1]*za[o] + ew[2]*right;
    gate[b*NC+o] = sigf(acc + fcb[o] + ye);
  }
}

// ---------------- K4: bf16 MFMA GEMM, z-batched; optional XCD chunked swizzle ----------------
__global__ __launch_bounds__(256) void k_gemm_bf16(
    const ushort* __restrict__ A, int lda, long sAz,
    const ushort* __restrict__ Bw, int ldb, long sBz, int K,
    ushort* __restrict__ C0, int ldc0, ushort* __restrict__ C1, int ldc1,
    int nsplit, long sCz,
    float* __restrict__ Cf, int ldcf, const float* __restrict__ bias, int swz)
{
  __shared__ __align__(16) ushort Asm[128*64];
  __shared__ __align__(16) ushort Bsm[128*64];
  const int z = blockIdx.z;
  A  += (size_t)z*sAz;
  Bw += (size_t)z*sBz;
  if (C0) C0 += (size_t)z*sCz;
  if (C1) C1 += (size_t)z*sCz;
  int bx = blockIdx.x, by = blockIdx.y;
  if (swz){
    int nx = gridDim.x, nwg = nx * gridDim.y;   // requires nwg % 8 == 0
    int lin = by*nx + bx;
    int cpx = nwg >> 3;
    int s = (lin & 7)*cpx + (lin >> 3);
    bx = s % nx; by = s / nx;
  }
  const int tid = threadIdx.x;
  const int lane = tid & 63, wid = tid >> 6;
  const int wm = wid >> 1, wn = wid & 1;
  const int m0 = by * 128, n0 = bx * 128;

  const ushort* ga[4]; const ushort* gb[4]; int ldst[4];
  #pragma unroll
  for (int j=0;j<4;j++){
    int c = tid + 256*j;
    int r = c >> 3;
    int kb = ((c & 7) << 4) ^ ((r & 7) << 4);
    ga[j] = A  + (size_t)(m0 + r)*lda + (kb >> 1);
    gb[j] = Bw + (size_t)(n0 + r)*ldb + (kb >> 1);
    ldst[j] = c * 8;
  }

  f32x4 acc[4][4];
  #pragma unroll
  for (int i=0;i<4;i++)
    #pragma unroll
    for (int j=0;j<4;j++) acc[i][j] = (f32x4){0.f,0.f,0.f,0.f};

  const int lc = lane & 15;
  const int kgrp = (lane >> 4) << 4;

  for (int k0 = 0; k0 < K; k0 += 64){
    #pragma unroll
    for (int j=0;j<4;j++) gload16(ga[j] + k0, Asm + ldst[j]);
    #pragma unroll
    for (int j=0;j<4;j++) gload16(gb[j] + k0, Bsm + ldst[j]);
    __syncthreads();
    #pragma unroll
    for (int kk=0; kk<2; kk++){
      bf16x8 af[4], bfr[4];
      #pragma unroll
      for (int i=0;i<4;i++){
        int ra = wm*64 + i*16 + lc;
        int kb = kk*64 + kgrp;
        af[i] = *(const bf16x8*)((const char*)Asm + ra*128 + (kb ^ ((ra&7)<<4)));
        int rb = wn*64 + i*16 + lc;
        bfr[i] = *(const bf16x8*)((const char*)Bsm + rb*128 + (kb ^ ((rb&7)<<4)));
      }
      #pragma unroll
      for (int i=0;i<4;i++)
        #pragma unroll
        for (int j=0;j<4;j++)
          acc[i][j] = __builtin_amdgcn_mfma_f32_16x16x32_bf16(af[i], bfr[j], acc[i][j], 0, 0, 0);
    }
    __syncthreads();
  }

  const int lr = (lane >> 4) * 4;
  if (Cf){
    #pragma unroll
    for (int i=0;i<4;i++)
      #pragma unroll
      for (int j=0;j<4;j++){
        int row = m0 + wm*64 + i*16 + lr;
        int col = n0 + wn*64 + j*16 + lc;
        float bv = bias ? bias[col] : 0.f;
        #pragma unroll
        for (int r=0;r<4;r++)
          Cf[(size_t)(row+r)*ldcf + col] = acc[i][j][r] + bv;
      }
  } else {
    #pragma unroll
    for (int i=0;i<4;i++)
      #pragma unroll
      for (int j=0;j<4;j++){
        int row = m0 + wm*64 + i*16 + lr;
        int col = n0 + wn*64 + j*16 + lc;
        #pragma unroll
        for (int r=0;r<4;r++){
          ushort hv = f2b(acc[i][j][r]);
          if (col < nsplit) C0[(size_t)(row+r)*ldc0 + col] = hv;
          else              C1[(size_t)(row+r)*ldc1 + col - nsplit] = hv;
        }
      }
  }
}

// ---------------- K5: conv3x3+SiLU from LDS halo + x_proj via MFMA ----------------
__global__ __launch_bounds__(256) void k_convxp(const ushort* __restrict__ xc,
    const float* __restrict__ cw, const float* __restrict__ cb,
    const ushort* __restrict__ xpw_b, ushort* __restrict__ u, float* __restrict__ xd){
  __shared__ __align__(16) ushort xin[4*32*128];
  __shared__ __align__(16) ushort su[64][136];
  int g = blockIdx.z, tid = threadIdx.x;
  int blk = blockIdx.x;
  int bimg = blk >> 4, rp = blk & 15;
  int t0 = blk * 64;
  const ushort* xcg = xc + (size_t)g*NTOK*ND;

  #pragma unroll
  for (int j=0;j<8;j++){
    int c = tid + 256*j;
    int r = c >> 9;
    int rest = c & 511;
    int gr = 2*rp + r - 1;
    gr = min(max(gr, 0), 31);
    int w = rest >> 4, p = rest & 15;
    gload16(xcg + ((size_t)((bimg<<10) | (gr<<5) | w))*ND + p*8, (ushort*)xin + c*8);
  }

  int p = tid & 15, d0 = p*8;
  float w_[9][8]; float bias[8];
  {
    const float* wk = cw + (size_t)(g*ND + d0)*9;
    #pragma unroll
    for (int j=0;j<8;j++)
      #pragma unroll
      for (int k9=0;k9<9;k9++) w_[k9][j] = wk[j*9+k9];
    const float* cbp = cb + g*ND + d0;
    #pragma unroll
    for (int j=0;j<8;j++) bias[j] = cbp[j];
  }
  __syncthreads();

  #pragma unroll
  for (int pass=0; pass<4; pass++){
    int lt = pass*16 + (tid>>4);
    int hl = lt >> 5, w = lt & 31;
    int t = t0 + lt;
    float acc[8];
    #pragma unroll
    for (int j=0;j<8;j++) acc[j] = bias[j];
    #pragma unroll
    for (int kh=0;kh<3;kh++){
      int gr = 2*rp + hl + kh - 1;
      if (gr < 0 || gr >= 32) continue;
      #pragma unroll
      for (int kw=0;kw<3;kw++){
        int w2 = w + kw - 1;
        if (w2 < 0 || w2 >= 32) continue;
        bf16x8 v = *(const bf16x8*)&xin[((hl+kh)*32 + w2)*128 + d0];
        #pragma unroll
        for (int j=0;j<8;j++) acc[j] = fmaf(b2f(((ushort*)&v)[j]), w_[kh*3+kw][j], acc[j]);
      }
    }
    bf16x8 o8;
    #pragma unroll
    for (int j=0;j<8;j++){
      float uv = acc[j] * sigf(acc[j]);
      ((ushort*)&o8)[j] = f2b(uv);
    }
    *(bf16x8*)(u + ((size_t)g*NTOK + t)*ND + d0) = o8;
    *(bf16x8*)&su[lt][d0] = o8;
  }
  __syncthreads();

  int lane = tid & 63, wv = tid >> 6;
  int c = lane & 15;
  int kg = (lane >> 4) * 8;
  int cc = c < 10 ? c : 0;
  f32x4 acc4 = (f32x4){0.f,0.f,0.f,0.f};
  #pragma unroll
  for (int ks=0; ks<4; ks++){
    bf16x8 af = *(const bf16x8*)&su[wv*16 + (lane & 15)][ks*32 + kg];
    bf16x8 bfv = *(const bf16x8*)(xpw_b + (size_t)(g*10+cc)*128 + ks*32 + kg);
    if (c >= 10) bfv = (bf16x8){0,0,0,0,0,0,0,0};
    acc4 = __builtin_amdgcn_mfma_f32_16x16x32_bf16(af, bfv, acc4, 0, 0, 0);
  }
  if (c < 10){
    #pragma unroll
    for (int r=0;r<4;r++){
      int row = (lane >> 4)*4 + r;
      int t = t0 + wv*16 + row;
      xd[((size_t)g*NTOK + t)*12 + c] = acc4[r];
    }
  }
}

// ---------------- scan helpers ----------------
struct ScanCtx {
  float Ad, dtb_d;
  float w[8];
};

__device__ __forceinline__ float delta_of(const ScanCtx& c,
    const float4& x0, const float4& x1){
  float a = c.dtb_d;
  a = fmaf(x0.x, c.w[0], a); a = fmaf(x0.y, c.w[1], a);
  a = fmaf(x0.z, c.w[2], a); a = fmaf(x0.w, c.w[3], a);
  a = fmaf(x1.x, c.w[4], a); a = fmaf(x1.y, c.w[5], a);
  a = fmaf(x1.z, c.w[6], a); a = fmaf(x1.w, c.w[7], a);
  return (a > 15.f) ? a : flog(1.f + fexp(a));
}

// ---------------- K6: scan pass 1 ----------------
__global__ __launch_bounds__(128) void k_scan1(const ushort* __restrict__ u,
    const float* __restrict__ xd, const float* __restrict__ Alog,
    const float* __restrict__ dtw, const float* __restrict__ dtb,
    float* __restrict__ chA, float* __restrict__ chB){
  int d = threadIdx.x, g = blockIdx.z;
  int b = blockIdx.x >> 6, ch = blockIdx.x & 63;
  ScanCtx c;
  c.Ad = -fexp(Alog[g*ND+d]);
  c.dtb_d = dtb[g*ND+d];
  const float4* wr = (const float4*)(dtw + (size_t)(g*ND+d)*8);
  float4 w0 = wr[0], w1 = wr[1];
  c.w[0]=w0.x;c.w[1]=w0.y;c.w[2]=w0.z;c.w[3]=w0.w;
  c.w[4]=w1.x;c.w[5]=w1.y;c.w[6]=w1.z;c.w[7]=w1.w;
  float h = 0.f, ap = 1.f;
  int l0 = ch*CST;
  #pragma unroll 4
  for (int s=0;s<CST;s++){
    int pp = perm_pos(g, l0 + s);
    size_t base = (size_t)g*NTOK + ((b<<10)|pp);
    float uv = b2f(u[base*ND + d]);
    const float4* xr = (const float4*)(xd + base*12);
    float4 x0 = xr[0], x1 = xr[1], x2 = xr[2];
    float dl = delta_of(c, x0, x1);
    float av = fexp(dl * c.Ad);
    h = fmaf(av, h, dl*x2.x*uv);
    ap *= av;
  }
  size_t o = (((size_t)g*16 + b)*NCH + ch)*ND + d;
  chA[o]=ap; chB[o]=h;
}

// ---------------- K8: scan pass 3 — inlined prefix combine + replay (bf16 y out) ----------------
__global__ __launch_bounds__(128) void k_scan3(const ushort* __restrict__ u,
    const float* __restrict__ xd, const float* __restrict__ Alog,
    const float* __restrict__ dtw, const float* __restrict__ dtb,
    const float* __restrict__ Dp, const float* __restrict__ chA,
    const float* __restrict__ chB, ushort* __restrict__ y){
  int d = threadIdx.x, g = blockIdx.z;
  int b = blockIdx.x >> 6, ch = blockIdx.x & 63;
  ScanCtx c;
  c.Ad = -fexp(Alog[g*ND+d]);
  c.dtb_d = dtb[g*ND+d];
  float Dd = Dp[g*ND+d];
  const float4* wr = (const float4*)(dtw + (size_t)(g*ND+d)*8);
  float4 w0 = wr[0], w1 = wr[1];
  c.w[0]=w0.x;c.w[1]=w0.y;c.w[2]=w0.z;c.w[3]=w0.w;
  c.w[4]=w1.x;c.w[5]=w1.y;c.w[6]=w1.z;c.w[7]=w1.w;
  // prefix combine over chunks 0..ch-1 (chA/chB are L2-resident, 2 MB)
  size_t cbase = (((size_t)g*16 + b)*NCH)*ND + d;
  float h = 0.f;
  for (int k=0;k<ch;k++){
    size_t o = cbase + (size_t)k*ND;
    h = fmaf(chA[o], h, chB[o]);
  }
  int l0 = ch*CST;
  #pragma unroll 4
  for (int s=0;s<CST;s++){
    int pp = perm_pos(g, l0 + s);
    size_t base = (size_t)g*NTOK + ((b<<10)|pp);
    float uv = b2f(u[base*ND + d]);
    const float4* xr = (const float4*)(xd + base*12);
    float4 x0 = xr[0], x1 = xr[1], x2 = xr[2];
    float dl = delta_of(c, x0, x1);
    float av = fexp(dl * c.Ad);
    h = fmaf(av, h, dl*x2.x*uv);
    y[base*ND + d] = f2b(fmaf(h, x2.y, Dd*uv));
  }
}

// ---------------- K9: out-LN(128) * SiLU(z); bf16 in/out ----------------
__global__ __launch_bounds__(256) void k_yo(const ushort* __restrict__ y,
    const ushort* __restrict__ zg, const float* __restrict__ onw,
    const float* __restrict__ onb, ushort* __restrict__ yo){
  int tid = threadIdx.x, g = blockIdx.z;
  int lt = tid >> 4, p = tid & 15;
  int t = blockIdx.x*16 + lt;
  size_t base = ((size_t)g*NTOK + t)*ND + p*8;
  bf16x8 yv8 = *(const bf16x8*)(y + base);
  float e[8];
  float s = 0.f, sq = 0.f;
  #pragma unroll
  for (int i=0;i<8;i++){
    e[i] = b2f(((ushort*)&yv8)[i]);
    s += e[i]; sq += e[i]*e[i];
  }
  #pragma unroll
  for (int o=1;o<16;o<<=1){ s += __shfl_xor(s,o); sq += __shfl_xor(sq,o); }
  float m = s*(1.f/ND);
  float var = sq*(1.f/ND) - m*m;
  float rs = rsqrtf(var + 1e-5f);
  const float4* wr = (const float4*)(onw + g*ND + p*8);
  const float4* br = (const float4*)(onb + g*ND + p*8);
  float4 w0 = wr[0], w1 = wr[1], b0 = br[0], b1 = br[1];
  float wv8[8] = {w0.x,w0.y,w0.z,w0.w,w1.x,w1.y,w1.z,w1.w};
  float bv8[8] = {b0.x,b0.y,b0.z,b0.w,b1.x,b1.y,b1.z,b1.w};
  bf16x8 zv = *(const bf16x8*)(zg + base);
  bf16x8 o8;
  #pragma unroll
  for (int i=0;i<8;i++){
    float yn = (e[i]-m)*rs*wv8[i]+bv8[i];
    float z = b2f(((ushort*)&zv)[i]);
    ((ushort*)&o8)[i] = f2b(yn * z * sigf(z));
  }
  *(bf16x8*)(yo + base) = o8;
}

// ---------------- K10: skip*xh*gate then LN(512); wave-per-token ----------------
__global__ __launch_bounds__(256) void k_gateln(const ushort* __restrict__ ybuf,
    const ushort* __restrict__ xn, const float* __restrict__ gate,
    const float* __restrict__ skip, const float* __restrict__ w,
    const float* __restrict__ b, ushort* __restrict__ out){
  int wv = threadIdx.x >> 6, lane = threadIdx.x & 63;
  int t = blockIdx.x*4 + wv, bb = t >> 10;
  float ss = skip[0];
  size_t o0 = (size_t)t*NC + lane*8;
  bf16x8 yv = *(const bf16x8*)(ybuf + o0);
  bf16x8 xv = *(const bf16x8*)(xn + o0);
  const float4* gr = (const float4*)(gate + bb*NC + lane*8);
  float4 g0 = gr[0], g1 = gr[1];
  float gv8[8] = {g0.x,g0.y,g0.z,g0.w,g1.x,g1.y,g1.z,g1.w};
  float e[8];
  float s = 0.f, sq = 0.f;
  #pragma unroll
  for (int i=0;i<8;i++){
    e[i] = b2f(((ushort*)&yv)[i]) * ss * b2f(((ushort*)&xv)[i]) * gv8[i];
    s += e[i]; sq += e[i]*e[i];
  }
  #pragma unroll
  for (int o=1;o<64;o<<=1){ s += __shfl_xor(s,o); sq += __shfl_xor(sq,o); }
  float m = s*(1.f/NC);
  float var = sq*(1.f/NC) - m*m;
  float rs = rsqrtf(var + 1e-5f);
  const float4* wr = (const float4*)(w + lane*8);
  const float4* br = (const float4*)(b + lane*8);
  float4 w0 = wr[0], w1 = wr[1], b0 = br[0], b1 = br[1];
  float wv8[8] = {w0.x,w0.y,w0.z,w0.w,w1.x,w1.y,w1.z,w1.w};
  float bv8[8] = {b0.x,b0.y,b0.z,b0.w,b1.x,b1.y,b1.z,b1.w};
  bf16x8 o8;
  #pragma unroll
  for (int i=0;i<8;i++) ((ushort*)&o8)[i] = f2b((e[i]-m)*rs*wv8[i]+bv8[i]);
  *(bf16x8*)(out + o0) = o8;
}

extern "C" void kernel_launch(void* const* d_in, const int* in_sizes, int n_in,
                              void* d_out, int out_size, void* d_ws, size_t ws_size,
                              hipStream_t stream) {
  const float* x          = (const float*)d_in[0];
  const float* norm_w     = (const float*)d_in[3];
  const float* norm_b     = (const float*)d_in[4];
  const float* fc_w       = (const float*)d_in[5];
  const float* fc_b       = (const float*)d_in[6];
  const float* eca_w      = (const float*)d_in[7];
  const float* skip_scale = (const float*)d_in[8];
  const float* proj_w     = (const float*)d_in[9];
  const float* proj_b     = (const float*)d_in[10];
  const float* in_proj_w  = (const float*)d_in[11];
  const float* conv_w     = (const float*)d_in[12];
  const float* conv_b     = (const float*)d_in[13];
  const float* x_proj_w   = (const float*)d_in[14];
  const float* dt_proj_w  = (const float*)d_in[15];
  const float* dt_proj_b  = (const float*)d_in[16];
  const float* A_log      = (const float*)d_in[17];
  const float* D_param    = (const float*)d_in[18];
  const float* out_norm_w = (const float*)d_in[19];
  const float* out_norm_b = (const float*)d_in[20];
  const float* out_proj_w = (const float*)d_in[21];
  float* out = (float*)d_out;
  float* ws  = (float*)d_ws;

  // ---- workspace layout (float units) — disjoint intervals ----
  ushort* xn_b   = (ushort*)(ws);                  // [0,        4194304)
  ushort* ybuf_b = (ushort*)(ws + 4194304);        // [4194304,  8388608)
  ushort* xc4    = (ushort*)(ws + 8388608);        // [8388608, 12582912)
  ushort* zg4    = (ushort*)(ws + 12582912);       // [12582912,16777216)
  ushort* yo4    = (ushort*)(ws + 16777216);       // [16777216,20971520)
  ushort* u4b    = (ushort*)(ws + 20971520);       // [20971520,25165824)
  ushort* y4b    = (ushort*)(ws + 25165824);       // [25165824,29360128)
  float*  xd4    = ws + 29360128;                  // [29360128,30146560)
  float*  chA    = ws + 30146560;                  // [30146560,30670848)
  float*  chB    = ws + 30670848;                  // [30670848,31195136)
  float*  zavg   = ws + 31719424;                  // +8192
  float*  gatep  = ws + 31727616;                  // +8192
  float*  part   = ws + 31735808;                  // +262144 -> 31997952
  ushort* wb_in  = (ushort*)(ws + 31997952);       // 131072 bf16
  ushort* wb_out = (ushort*)(ws + 32063488);       // 65536 bf16
  ushort* wb_prj = (ushort*)(ws + 32096256);       // 262144 bf16
  ushort* wb_xp  = (ushort*)(ws + 32227328);       // 5120 bf16
  ushort* xmn_b  = (ushort*)(ws + 32229888);       // [32229888,36424192)

  // LN + folded weight conversion (4096 blocks * 256 thr >= 463872 elems)
  k_ln512<<<dim3(NTOK/4), dim3(256), 0, stream>>>(x, norm_w, norm_b, xn_b,
      in_proj_w, 131072, wb_in, out_proj_w, 65536, wb_out,
      proj_w, 262144, wb_prj, x_proj_w, 5120, wb_xp);
  k_cm1<<<dim3(512), dim3(512), 0, stream>>>(xn_b, part);
  k_cm2<<<dim3(16), dim3(512), 0, stream>>>(part, zavg);
  k_gate<<<dim3(16*128), dim3(256), 0, stream>>>(zavg, fc_w, fc_b, eca_w, gatep);

  // in_proj (batched over g)
  k_gemm_bf16<<<dim3(2,128,4), dim3(256), 0, stream>>>(
      xn_b, NC, 128, wb_in, 128, 256*128, 128,
      xc4, 128, zg4, 128, 128, (long)NTOK*128,
      (float*)nullptr, 0, (const float*)nullptr, 0);

  k_convxp<<<dim3(NTOK/64,1,4), dim3(256), 0, stream>>>(
      xc4, conv_w, conv_b, wb_xp, u4b, xd4);

  k_scan1<<<dim3(16*NCH,1,4), dim3(128), 0, stream>>>(
      u4b, xd4, A_log, dt_proj_w, dt_proj_b, chA, chB);
  // scan3 with inlined prefix combine (no scomb kernel, no hIn buffer)
  k_scan3<<<dim3(16*NCH,1,4), dim3(128), 0, stream>>>(
      u4b, xd4, A_log, dt_proj_w, dt_proj_b, D_param, chA, chB, y4b);

  k_yo<<<dim3(NTOK/16,1,4), dim3(256), 0, stream>>>(
      y4b, zg4, out_norm_w, out_norm_b, yo4);

  // out_proj (batched)
  k_gemm_bf16<<<dim3(1,128,4), dim3(256), 0, stream>>>(
      yo4, 128, (long)NTOK*128, wb_out, 128, 128*128, 128,
      ybuf_b, NC, ybuf_b, NC, 1<<30, 128,
      (float*)nullptr, 0, (const float*)nullptr, 0);

  k_gateln<<<dim3(NTOK/4), dim3(256), 0, stream>>>(
      ybuf_b, xn_b, gatep, skip_scale, norm_w, norm_b, xmn_b);

  // final proj + XCD chunked swizzle (512 % 8 == 0)
  k_gemm_bf16<<<dim3(4,128,1), dim3(256), 0, stream>>>(
      xmn_b, NC, 0, wb_prj, NC, 0, NC,
      (ushort*)nullptr, 0, (ushort*)nullptr, 0, 0, 0,
      out, NC, proj_b, 1);
}

// Round 14
// 135.416 us; speedup vs baseline: 1.1030x; 1.1030x over previous
//
#include <hip/hip_runtime.h>
#include <math.h>

// B=16, H=W=32, C=512, D=128/group, S=1, R=8
#define NTOK 16384
#define NC 512
#define ND 128
#define NCH 64   // scan chunks per (b,g)
#define CST 16   // steps per chunk

typedef __attribute__((ext_vector_type(8))) short bf16x8;
typedef __attribute__((ext_vector_type(4))) float f32x4;

#define LOG2E 1.4426950408889634f
#define LN2   0.6931471805599453f

__device__ __forceinline__ float fexp(float x){ return __builtin_amdgcn_exp2f(x * LOG2E); }
__device__ __forceinline__ float flog(float x){ return __builtin_amdgcn_logf(x) * LN2; }
__device__ __forceinline__ float sigf(float x){ return 1.f/(1.f + fexp(-x)); }

__device__ __forceinline__ float b2f(ushort u){ unsigned x = ((unsigned)u)<<16; return __builtin_bit_cast(float,x); }
__device__ __forceinline__ ushort f2b(float f){
  unsigned u = __builtin_bit_cast(unsigned,f);
  u += 0x7fff + ((u>>16)&1);
  return (ushort)(u>>16);
}

__device__ __forceinline__ int perm_pos(int g, int l){
  switch(g){
    case 0: return l;
    case 1: return ((l & 31) << 5) | (l >> 5);
    case 2: return 1023 - l;
    default:{ int ll = 1023 - l; return ((ll & 31) << 5) | (ll >> 5); }
  }
}

__device__ __forceinline__ void gload16(const void* g, void* l){
  __builtin_amdgcn_global_load_lds((const __attribute__((address_space(1))) void*)g,
                                   (__attribute__((address_space(3))) void*)l, 16, 0, 0);
}

// ---------------- fp32 -> bf16 convert, 4 arrays ----------------
__global__ __launch_bounds__(256) void k_tobf16_4(
    const float* __restrict__ s1, int n1, ushort* __restrict__ d1,
    const float* __restrict__ s2, int n2, ushort* __restrict__ d2,
    const float* __restrict__ s3, int n3, ushort* __restrict__ d3,
    const float* __restrict__ s4, int n4, ushort* __restrict__ d4){
  int i = blockIdx.x*256 + threadIdx.x;
  if (i < n1) d1[i] = f2b(s1[i]);
  else if (i < n1+n2) d2[i-n1] = f2b(s2[i-n1]);
  else if (i < n1+n2+n3) d3[i-n1-n2] = f2b(s3[i-n1-n2]);
  else if (i < n1+n2+n3+n4) d4[i-n1-n2-n3] = f2b(s4[i-n1-n2-n3]);
}

// ---------------- K1: LayerNorm over C=512, wave-per-token, bf16 out ----------------
__global__ __launch_bounds__(256) void k_ln512(const float* __restrict__ x,
    const float* __restrict__ w, const float* __restrict__ b, ushort* __restrict__ out){
  int wv = threadIdx.x >> 6, lane = threadIdx.x & 63;
  int t = blockIdx.x*4 + wv;
  const float* xr = x + (size_t)t*NC + lane*8;
  float4 a = *(const float4*)xr;
  float4 c = *(const float4*)(xr+4);
  float e[8] = {a.x,a.y,a.z,a.w,c.x,c.y,c.z,c.w};
  float s = 0.f, sq = 0.f;
  #pragma unroll
  for (int i=0;i<8;i++){ s += e[i]; sq += e[i]*e[i]; }
  #pragma unroll
  for (int o=1;o<64;o<<=1){ s += __shfl_xor(s,o); sq += __shfl_xor(sq,o); }
  float m = s*(1.f/NC);
  float var = sq*(1.f/NC) - m*m;
  float rs = rsqrtf(var + 1e-5f);
  const float4* wr = (const float4*)(w + lane*8);
  const float4* br = (const float4*)(b + lane*8);
  float4 w0 = wr[0], w1 = wr[1], b0 = br[0], b1 = br[1];
  float wv8[8] = {w0.x,w0.y,w0.z,w0.w,w1.x,w1.y,w1.z,w1.w};
  float bv8[8] = {b0.x,b0.y,b0.z,b0.w,b1.x,b1.y,b1.z,b1.w};
  bf16x8 o8;
  #pragma unroll
  for (int i=0;i<8;i++) ((ushort*)&o8)[i] = f2b((e[i]-m)*rs*wv8[i]+bv8[i]);
  *(bf16x8*)(out + (size_t)t*NC + lane*8) = o8;
}

// ---------------- K2: column mean, 2-stage ----------------
__global__ __launch_bounds__(512) void k_cm1(const ushort* __restrict__ xn,
    float* __restrict__ part){
  int c = threadIdx.x;
  const ushort* base = xn + ((size_t)blockIdx.x*32)*NC + c;
  float acc = 0.f;
  for (int n=0;n<32;n++) acc += b2f(base[(size_t)n*NC]);
  part[(size_t)blockIdx.x*NC + c] = acc;
}
__global__ __launch_bounds__(512) void k_cm2(const float* __restrict__ part,
    float* __restrict__ zavg){
  int b = blockIdx.x, c = threadIdx.x;
  float acc = 0.f;
  for (int i=0;i<32;i++) acc += part[(size_t)(b*32+i)*NC + c];
  zavg[b*NC+c] = acc * (1.f/1024.f);
}

// ---------------- K3: ECA + FC gate; wave-per-output ----------------
__global__ __launch_bounds__(256) void k_gate(const float* __restrict__ zavg,
    const float* __restrict__ fcw, const float* __restrict__ fcb,
    const float* __restrict__ ew, float* __restrict__ gate){
  __shared__ float za[NC];
  int b = blockIdx.x >> 7, og = blockIdx.x & 127;
  int tid = threadIdx.x, lane = tid & 63, wv = tid >> 6;
  za[tid]     = zavg[b*NC + tid];
  za[tid+256] = zavg[b*NC + tid + 256];
  __syncthreads();
  int o = og*4 + wv;
  const float* wr = fcw + (size_t)o*NC;
  float acc = 0.f;
  #pragma unroll
  for (int i=0;i<8;i++) acc += za[lane + i*64]*wr[lane + i*64];
  #pragma unroll
  for (int off=1;off<64;off<<=1) acc += __shfl_xor(acc, off);
  if (lane==0){
    float left  = (o>0)    ? za[o-1] : 0.f;
    float right = (o<NC-1) ? za[o+1] : 0.f;
    float ye = ew[0]*left + ew[1]*za[o] + ew[2]*right;
    gate[b*NC+o] = sigf(acc + fcb[o] + ye);
  }
}

// ---------------- K4: bf16 MFMA GEMM, z-batched; optional XCD chunked swizzle ----------------
__global__ __launch_bounds__(256) void k_gemm_bf16(
    const ushort* __restrict__ A, int lda, long sAz,
    const ushort* __restrict__ Bw, int ldb, long sBz, int K,
    ushort* __restrict__ C0, int ldc0, ushort* __restrict__ C1, int ldc1,
    int nsplit, long sCz,
    float* __restrict__ Cf, int ldcf, const float* __restrict__ bias, int swz)
{
  __shared__ __align__(16) ushort Asm[128*64];
  __shared__ __align__(16) ushort Bsm[128*64];
  const int z = blockIdx.z;
  A  += (size_t)z*sAz;
  Bw += (size_t)z*sBz;
  if (C0) C0 += (size_t)z*sCz;
  if (C1) C1 += (size_t)z*sCz;
  int bx = blockIdx.x, by = blockIdx.y;
  if (swz){
    int nx = gridDim.x, nwg = nx * gridDim.y;   // requires nwg % 8 == 0
    int lin = by*nx + bx;
    int cpx = nwg >> 3;
    int s = (lin & 7)*cpx + (lin >> 3);
    bx = s % nx; by = s / nx;
  }
  const int tid = threadIdx.x;
  const int lane = tid & 63, wid = tid >> 6;
  const int wm = wid >> 1, wn = wid & 1;
  const int m0 = by * 128, n0 = bx * 128;

  const ushort* ga[4]; const ushort* gb[4]; int ldst[4];
  #pragma unroll
  for (int j=0;j<4;j++){
    int c = tid + 256*j;
    int r = c >> 3;
    int kb = ((c & 7) << 4) ^ ((r & 7) << 4);
    ga[j] = A  + (size_t)(m0 + r)*lda + (kb >> 1);
    gb[j] = Bw + (size_t)(n0 + r)*ldb + (kb >> 1);
    ldst[j] = c * 8;
  }

  f32x4 acc[4][4];
  #pragma unroll
  for (int i=0;i<4;i++)
    #pragma unroll
    for (int j=0;j<4;j++) acc[i][j] = (f32x4){0.f,0.f,0.f,0.f};

  const int lc = lane & 15;
  const int kgrp = (lane >> 4) << 4;

  for (int k0 = 0; k0 < K; k0 += 64){
    #pragma unroll
    for (int j=0;j<4;j++) gload16(ga[j] + k0, Asm + ldst[j]);
    #pragma unroll
    for (int j=0;j<4;j++) gload16(gb[j] + k0, Bsm + ldst[j]);
    __syncthreads();
    #pragma unroll
    for (int kk=0; kk<2; kk++){
      bf16x8 af[4], bfr[4];
      #pragma unroll
      for (int i=0;i<4;i++){
        int ra = wm*64 + i*16 + lc;
        int kb = kk*64 + kgrp;
        af[i] = *(const bf16x8*)((const char*)Asm + ra*128 + (kb ^ ((ra&7)<<4)));
        int rb = wn*64 + i*16 + lc;
        bfr[i] = *(const bf16x8*)((const char*)Bsm + rb*128 + (kb ^ ((rb&7)<<4)));
      }
      #pragma unroll
      for (int i=0;i<4;i++)
        #pragma unroll
        for (int j=0;j<4;j++)
          acc[i][j] = __builtin_amdgcn_mfma_f32_16x16x32_bf16(af[i], bfr[j], acc[i][j], 0, 0, 0);
    }
    __syncthreads();
  }

  const int lr = (lane >> 4) * 4;
  if (Cf){
    #pragma unroll
    for (int i=0;i<4;i++)
      #pragma unroll
      for (int j=0;j<4;j++){
        int row = m0 + wm*64 + i*16 + lr;
        int col = n0 + wn*64 + j*16 + lc;
        float bv = bias ? bias[col] : 0.f;
        #pragma unroll
        for (int r=0;r<4;r++)
          Cf[(size_t)(row+r)*ldcf + col] = acc[i][j][r] + bv;
      }
  } else {
    #pragma unroll
    for (int i=0;i<4;i++)
      #pragma unroll
      for (int j=0;j<4;j++){
        int row = m0 + wm*64 + i*16 + lr;
        int col = n0 + wn*64 + j*16 + lc;
        #pragma unroll
        for (int r=0;r<4;r++){
          ushort hv = f2b(acc[i][j][r]);
          if (col < nsplit) C0[(size_t)(row+r)*ldc0 + col] = hv;
          else              C1[(size_t)(row+r)*ldc1 + col - nsplit] = hv;
        }
      }
  }
}

// ---------------- K5: conv3x3+SiLU from LDS halo + x_proj via MFMA ----------------
__global__ __launch_bounds__(256) void k_convxp(const ushort* __restrict__ xc,
    const float* __restrict__ cw, const float* __restrict__ cb,
    const ushort* __restrict__ xpw_b, ushort* __restrict__ u, float* __restrict__ xd){
  __shared__ __align__(16) ushort xin[4*32*128];
  __shared__ __align__(16) ushort su[64][136];
  int g = blockIdx.z, tid = threadIdx.x;
  int blk = blockIdx.x;
  int bimg = blk >> 4, rp = blk & 15;
  int t0 = blk * 64;
  const ushort* xcg = xc + (size_t)g*NTOK*ND;

  #pragma unroll
  for (int j=0;j<8;j++){
    int c = tid + 256*j;
    int r = c >> 9;
    int rest = c & 511;
    int gr = 2*rp + r - 1;
    gr = min(max(gr, 0), 31);
    int w = rest >> 4, p = rest & 15;
    gload16(xcg + ((size_t)((bimg<<10) | (gr<<5) | w))*ND + p*8, (ushort*)xin + c*8);
  }

  int p = tid & 15, d0 = p*8;
  float w_[9][8]; float bias[8];
  {
    const float* wk = cw + (size_t)(g*ND + d0)*9;
    #pragma unroll
    for (int j=0;j<8;j++)
      #pragma unroll
      for (int k9=0;k9<9;k9++) w_[k9][j] = wk[j*9+k9];
    const float* cbp = cb + g*ND + d0;
    #pragma unroll
    for (int j=0;j<8;j++) bias[j] = cbp[j];
  }
  __syncthreads();

  #pragma unroll
  for (int pass=0; pass<4; pass++){
    int lt = pass*16 + (tid>>4);
    int hl = lt >> 5, w = lt & 31;
    int t = t0 + lt;
    float acc[8];
    #pragma unroll
    for (int j=0;j<8;j++) acc[j] = bias[j];
    #pragma unroll
    for (int kh=0;kh<3;kh++){
      int gr = 2*rp + hl + kh - 1;
      if (gr < 0 || gr >= 32) continue;
      #pragma unroll
      for (int kw=0;kw<3;kw++){
        int w2 = w + kw - 1;
        if (w2 < 0 || w2 >= 32) continue;
        bf16x8 v = *(const bf16x8*)&xin[((hl+kh)*32 + w2)*128 + d0];
        #pragma unroll
        for (int j=0;j<8;j++) acc[j] = fmaf(b2f(((ushort*)&v)[j]), w_[kh*3+kw][j], acc[j]);
      }
    }
    bf16x8 o8;
    #pragma unroll
    for (int j=0;j<8;j++){
      float uv = acc[j] * sigf(acc[j]);
      ((ushort*)&o8)[j] = f2b(uv);
    }
    *(bf16x8*)(u + ((size_t)g*NTOK + t)*ND + d0) = o8;
    *(bf16x8*)&su[lt][d0] = o8;
  }
  __syncthreads();

  int lane = tid & 63, wv = tid >> 6;
  int c = lane & 15;
  int kg = (lane >> 4) * 8;
  int cc = c < 10 ? c : 0;
  f32x4 acc4 = (f32x4){0.f,0.f,0.f,0.f};
  #pragma unroll
  for (int ks=0; ks<4; ks++){
    bf16x8 af = *(const bf16x8*)&su[wv*16 + (lane & 15)][ks*32 + kg];
    bf16x8 bfv = *(const bf16x8*)(xpw_b + (size_t)(g*10+cc)*128 + ks*32 + kg);
    if (c >= 10) bfv = (bf16x8){0,0,0,0,0,0,0,0};
    acc4 = __builtin_amdgcn_mfma_f32_16x16x32_bf16(af, bfv, acc4, 0, 0, 0);
  }
  if (c < 10){
    #pragma unroll
    for (int r=0;r<4;r++){
      int row = (lane >> 4)*4 + r;
      int t = t0 + wv*16 + row;
      xd[((size_t)g*NTOK + t)*12 + c] = acc4[r];
    }
  }
}

// ---------------- scan helpers ----------------
struct ScanCtx {
  float Ad, dtb_d;
  float w[8];
};

__device__ __forceinline__ float delta_of(const ScanCtx& c,
    const float4& x0, const float4& x1){
  float a = c.dtb_d;
  a = fmaf(x0.x, c.w[0], a); a = fmaf(x0.y, c.w[1], a);
  a = fmaf(x0.z, c.w[2], a); a = fmaf(x0.w, c.w[3], a);
  a = fmaf(x1.x, c.w[4], a); a = fmaf(x1.y, c.w[5], a);
  a = fmaf(x1.z, c.w[6], a); a = fmaf(x1.w, c.w[7], a);
  return (a > 15.f) ? a : flog(1.f + fexp(a));
}

// ---------------- K6: scan pass 1 ----------------
__global__ __launch_bounds__(128) void k_scan1(const ushort* __restrict__ u,
    const float* __restrict__ xd, const float* __restrict__ Alog,
    const float* __restrict__ dtw, const float* __restrict__ dtb,
    float* __restrict__ chA, float* __restrict__ chB){
  int d = threadIdx.x, g = blockIdx.z;
  int b = blockIdx.x >> 6, ch = blockIdx.x & 63;
  ScanCtx c;
  c.Ad = -fexp(Alog[g*ND+d]);
  c.dtb_d = dtb[g*ND+d];
  const float4* wr = (const float4*)(dtw + (size_t)(g*ND+d)*8);
  float4 w0 = wr[0], w1 = wr[1];
  c.w[0]=w0.x;c.w[1]=w0.y;c.w[2]=w0.z;c.w[3]=w0.w;
  c.w[4]=w1.x;c.w[5]=w1.y;c.w[6]=w1.z;c.w[7]=w1.w;
  float h = 0.f, ap = 1.f;
  int l0 = ch*CST;
  #pragma unroll 4
  for (int s=0;s<CST;s++){
    int pp = perm_pos(g, l0 + s);
    size_t base = (size_t)g*NTOK + ((b<<10)|pp);
    float uv = b2f(u[base*ND + d]);
    const float4* xr = (const float4*)(xd + base*12);
    float4 x0 = xr[0], x1 = xr[1], x2 = xr[2];
    float dl = delta_of(c, x0, x1);
    float av = fexp(dl * c.Ad);
    h = fmaf(av, h, dl*x2.x*uv);
    ap *= av;
  }
  size_t o = (((size_t)g*16 + b)*NCH + ch)*ND + d;
  chA[o]=ap; chB[o]=h;
}

// ---------------- K7: combine over chunks ----------------
__global__ __launch_bounds__(128) void k_scomb(const float* __restrict__ chA,
    const float* __restrict__ chB, float* __restrict__ hIn){
  int b = blockIdx.x, g = blockIdx.z, d = threadIdx.x;
  size_t base = (((size_t)g*16 + b)*NCH)*ND + d;
  float hrun = 0.f;
  #pragma unroll
  for (int ch=0; ch<NCH; ch++){
    size_t o = base + (size_t)ch*ND;
    float a = chA[o], bb = chB[o];
    hIn[o] = hrun;
    hrun = fmaf(a, hrun, bb);
  }
}

// ---------------- K8: scan pass 3 (bf16 y out) ----------------
__global__ __launch_bounds__(128) void k_scan3(const ushort* __restrict__ u,
    const float* __restrict__ xd, const float* __restrict__ Alog,
    const float* __restrict__ dtw, const float* __restrict__ dtb,
    const float* __restrict__ Dp, const float* __restrict__ hIn,
    ushort* __restrict__ y){
  int d = threadIdx.x, g = blockIdx.z;
  int b = blockIdx.x >> 6, ch = blockIdx.x & 63;
  ScanCtx c;
  c.Ad = -fexp(Alog[g*ND+d]);
  c.dtb_d = dtb[g*ND+d];
  float Dd = Dp[g*ND+d];
  const float4* wr = (const float4*)(dtw + (size_t)(g*ND+d)*8);
  float4 w0 = wr[0], w1 = wr[1];
  c.w[0]=w0.x;c.w[1]=w0.y;c.w[2]=w0.z;c.w[3]=w0.w;
  c.w[4]=w1.x;c.w[5]=w1.y;c.w[6]=w1.z;c.w[7]=w1.w;
  float h = hIn[(((size_t)g*16 + b)*NCH + ch)*ND + d];
  int l0 = ch*CST;
  #pragma unroll 4
  for (int s=0;s<CST;s++){
    int pp = perm_pos(g, l0 + s);
    size_t base = (size_t)g*NTOK + ((b<<10)|pp);
    float uv = b2f(u[base*ND + d]);
    const float4* xr = (const float4*)(xd + base*12);
    float4 x0 = xr[0], x1 = xr[1], x2 = xr[2];
    float dl = delta_of(c, x0, x1);
    float av = fexp(dl * c.Ad);
    h = fmaf(av, h, dl*x2.x*uv);
    y[base*ND + d] = f2b(fmaf(h, x2.y, Dd*uv));
  }
}

// ---------------- K9: out-LN(128) * SiLU(z); bf16 in/out ----------------
__global__ __launch_bounds__(256) void k_yo(const ushort* __restrict__ y,
    const ushort* __restrict__ zg, const float* __restrict__ onw,
    const float* __restrict__ onb, ushort* __restrict__ yo){
  int tid = threadIdx.x, g = blockIdx.z;
  int lt = tid >> 4, p = tid & 15;
  int t = blockIdx.x*16 + lt;
  size_t base = ((size_t)g*NTOK + t)*ND + p*8;
  bf16x8 yv8 = *(const bf16x8*)(y + base);
  float e[8];
  float s = 0.f, sq = 0.f;
  #pragma unroll
  for (int i=0;i<8;i++){
    e[i] = b2f(((ushort*)&yv8)[i]);
    s += e[i]; sq += e[i]*e[i];
  }
  #pragma unroll
  for (int o=1;o<16;o<<=1){ s += __shfl_xor(s,o); sq += __shfl_xor(sq,o); }
  float m = s*(1.f/ND);
  float var = sq*(1.f/ND) - m*m;
  float rs = rsqrtf(var + 1e-5f);
  const float4* wr = (const float4*)(onw + g*ND + p*8);
  const float4* br = (const float4*)(onb + g*ND + p*8);
  float4 w0 = wr[0], w1 = wr[1], b0 = br[0], b1 = br[1];
  float wv8[8] = {w0.x,w0.y,w0.z,w0.w,w1.x,w1.y,w1.z,w1.w};
  float bv8[8] = {b0.x,b0.y,b0.z,b0.w,b1.x,b1.y,b1.z,b1.w};
  bf16x8 zv = *(const bf16x8*)(zg + base);
  bf16x8 o8;
  #pragma unroll
  for (int i=0;i<8;i++){
    float yn = (e[i]-m)*rs*wv8[i]+bv8[i];
    float z = b2f(((ushort*)&zv)[i]);
    ((ushort*)&o8)[i] = f2b(yn * z * sigf(z));
  }
  *(bf16x8*)(yo + base) = o8;
}

// ---------------- K10: skip*xh*gate then LN(512); wave-per-token ----------------
__global__ __launch_bounds__(256) void k_gateln(const ushort* __restrict__ ybuf,
    const ushort* __restrict__ xn, const float* __restrict__ gate,
    const float* __restrict__ skip, const float* __restrict__ w,
    const float* __restrict__ b, ushort* __restrict__ out){
  int wv = threadIdx.x >> 6, lane = threadIdx.x & 63;
  int t = blockIdx.x*4 + wv, bb = t >> 10;
  float ss = skip[0];
  size_t o0 = (size_t)t*NC + lane*8;
  bf16x8 yv = *(const bf16x8*)(ybuf + o0);
  bf16x8 xv = *(const bf16x8*)(xn + o0);
  const float4* gr = (const float4*)(gate + bb*NC + lane*8);
  float4 g0 = gr[0], g1 = gr[1];
  float gv8[8] = {g0.x,g0.y,g0.z,g0.w,g1.x,g1.y,g1.z,g1.w};
  float e[8];
  float s = 0.f, sq = 0.f;
  #pragma unroll
  for (int i=0;i<8;i++){
    e[i] = b2f(((ushort*)&yv)[i]) * ss * b2f(((ushort*)&xv)[i]) * gv8[i];
    s += e[i]; sq += e[i]*e[i];
  }
  #pragma unroll
  for (int o=1;o<64;o<<=1){ s += __shfl_xor(s,o); sq += __shfl_xor(sq,o); }
  float m = s*(1.f/NC);
  float var = sq*(1.f/NC) - m*m;
  float rs = rsqrtf(var + 1e-5f);
  const float4* wr = (const float4*)(w + lane*8);
  const float4* br = (const float4*)(b + lane*8);
  float4 w0 = wr[0], w1 = wr[1], b0 = br[0], b1 = br[1];
  float wv8[8] = {w0.x,w0.y,w0.z,w0.w,w1.x,w1.y,w1.z,w1.w};
  float bv8[8] = {b0.x,b0.y,b0.z,b0.w,b1.x,b1.y,b1.z,b1.w};
  bf16x8 o8;
  #pragma unroll
  for (int i=0;i<8;i++) ((ushort*)&o8)[i] = f2b((e[i]-m)*rs*wv8[i]+bv8[i]);
  *(bf16x8*)(out + o0) = o8;
}

extern "C" void kernel_launch(void* const* d_in, const int* in_sizes, int n_in,
                              void* d_out, int out_size, void* d_ws, size_t ws_size,
                              hipStream_t stream) {
  const float* x          = (const float*)d_in[0];
  const float* norm_w     = (const float*)d_in[3];
  const float* norm_b     = (const float*)d_in[4];
  const float* fc_w       = (const float*)d_in[5];
  const float* fc_b       = (const float*)d_in[6];
  const float* eca_w      = (const float*)d_in[7];
  const float* skip_scale = (const float*)d_in[8];
  const float* proj_w     = (const float*)d_in[9];
  const float* proj_b     = (const float*)d_in[10];
  const float* in_proj_w  = (const float*)d_in[11];
  const float* conv_w     = (const float*)d_in[12];
  const float* conv_b     = (const float*)d_in[13];
  const float* x_proj_w   = (const float*)d_in[14];
  const float* dt_proj_w  = (const float*)d_in[15];
  const float* dt_proj_b  = (const float*)d_in[16];
  const float* A_log      = (const float*)d_in[17];
  const float* D_param    = (const float*)d_in[18];
  const float* out_norm_w = (const float*)d_in[19];
  const float* out_norm_b = (const float*)d_in[20];
  const float* out_proj_w = (const float*)d_in[21];
  float* out = (float*)d_out;
  float* ws  = (float*)d_ws;

  // ---- workspace layout (float units) — disjoint intervals ----
  ushort* xn_b   = (ushort*)(ws);                  // [0,        4194304)
  ushort* ybuf_b = (ushort*)(ws + 4194304);        // [4194304,  8388608)
  ushort* xc4    = (ushort*)(ws + 8388608);        // [8388608, 12582912)
  ushort* zg4    = (ushort*)(ws + 12582912);       // [12582912,16777216)
  ushort* yo4    = (ushort*)(ws + 16777216);       // [16777216,20971520)
  ushort* u4b    = (ushort*)(ws + 20971520);       // [20971520,25165824)
  ushort* y4b    = (ushort*)(ws + 25165824);       // [25165824,29360128)
  float*  xd4    = ws + 29360128;                  // [29360128,30146560)
  float*  chA    = ws + 30146560;                  // [30146560,30670848)
  float*  chB    = ws + 30670848;                  // [30670848,31195136)
  float*  hIn    = ws + 31195136;                  // [31195136,31719424)
  float*  zavg   = ws + 31719424;                  // +8192
  float*  gatep  = ws + 31727616;                  // +8192
  float*  part   = ws + 31735808;                  // +262144 -> 31997952
  ushort* wb_in  = (ushort*)(ws + 31997952);       // 131072 bf16
  ushort* wb_out = (ushort*)(ws + 32063488);       // 65536 bf16
  ushort* wb_prj = (ushort*)(ws + 32096256);       // 262144 bf16
  ushort* wb_xp  = (ushort*)(ws + 32227328);       // 5120 bf16
  ushort* xmn_b  = (ushort*)(ws + 32229888);       // [32229888,36424192)

  k_ln512<<<dim3(NTOK/4), dim3(256), 0, stream>>>(x, norm_w, norm_b, xn_b);
  k_cm1<<<dim3(512), dim3(512), 0, stream>>>(xn_b, part);
  k_cm2<<<dim3(16), dim3(512), 0, stream>>>(part, zavg);
  k_gate<<<dim3(16*128), dim3(256), 0, stream>>>(zavg, fc_w, fc_b, eca_w, gatep);
  k_tobf16_4<<<dim3(1812), dim3(256), 0, stream>>>(
      in_proj_w, 131072, wb_in, out_proj_w, 65536, wb_out,
      proj_w, 262144, wb_prj, x_proj_w, 5120, wb_xp);

  // in_proj (batched over g)
  k_gemm_bf16<<<dim3(2,128,4), dim3(256), 0, stream>>>(
      xn_b, NC, 128, wb_in, 128, 256*128, 128,
      xc4, 128, zg4, 128, 128, (long)NTOK*128,
      (float*)nullptr, 0, (const float*)nullptr, 0);

  k_convxp<<<dim3(NTOK/64,1,4), dim3(256), 0, stream>>>(
      xc4, conv_w, conv_b, wb_xp, u4b, xd4);

  k_scan1<<<dim3(16*NCH,1,4), dim3(128), 0, stream>>>(
      u4b, xd4, A_log, dt_proj_w, dt_proj_b, chA, chB);
  k_scomb<<<dim3(16,1,4), dim3(128), 0, stream>>>(chA, chB, hIn);
  k_scan3<<<dim3(16*NCH,1,4), dim3(128), 0, stream>>>(
      u4b, xd4, A_log, dt_proj_w, dt_proj_b, D_param, hIn, y4b);

  k_yo<<<dim3(NTOK/16,1,4), dim3(256), 0, stream>>>(
      y4b, zg4, out_norm_w, out_norm_b, yo4);

  // out_proj (batched)
  k_gemm_bf16<<<dim3(1,128,4), dim3(256), 0, stream>>>(
      yo4, 128, (long)NTOK*128, wb_out, 128, 128*128, 128,
      ybuf_b, NC, ybuf_b, NC, 1<<30, 128,
      (float*)nullptr, 0, (const float*)nullptr, 0);

  k_gateln<<<dim3(NTOK/4), dim3(256), 0, stream>>>(
      ybuf_b, xn_b, gatep, skip_scale, norm_w, norm_b, xmn_b);

  // final proj + XCD chunked swizzle (512 % 8 == 0)
  k_gemm_bf16<<<dim3(4,128,1), dim3(256), 0, stream>>>(
      xmn_b, NC, 0, wb_prj, NC, 0, NC,
      (ushort*)nullptr, 0, (ushort*)nullptr, 0, 0, 0,
      out, NC, proj_b, 1);
}